// Round 8
// baseline (218.889 us; speedup 1.0000x reference)
//
#include <hip/hip_runtime.h>
#include <math.h>

#define NROWS 16384   // B*T
#define DDIM  2048
#define NEXP  16
#define RBLOCKS 1024  // router grid: 16 rows/block, 4 blocks/CU co-resident
#define WPB 4         // waves per 256-thread block
#define ZN (RBLOCKS * WPB)

__device__ __forceinline__ float fnoise(float x) {
    return copysignf(sqrtf(fabsf(x)), x);
}

// ws layout (float idx):
//   [32800, 36896)   zpartial [ZN] (one float per wave)
// (w_noisy/b_noisy workspace no longer used: prep is fused into the router)

// Fused router: the prep kernel is GONE. Each block stages its w chunk by
// loading raw weight + sigma_weight + eps_in, computing
//   w' = w + (sw * fo) * fi      (exact same expression tree as old prep)
// in registers, and ds_write_b128 into the LDS double buffer. T14 split:
// staging loads issue at chunk start, the FMA body covers their latency,
// compute+write happen at chunk end, __syncthreads publishes. This removes
// one kernel launch + one graph edge + the 384 KB w_noisy round-trip.
// R5-R7 evidence: sync structure / occupancy / staging mode are all neutral;
// the remaining tractable cost is the serial kernel chain (~60 us residual
// after fill + router in every round's accounting).
// Geometry (R6): 256 thr = 4 waves, 16 rows/block, 2 x 16 KiB LDS, 4
// blocks/CU. Inner FMA block / butterfly / epilogue byte-identical to the
// verified R0/R6 code.
__global__ __launch_bounds__(256, 4) void router_kernel(
        const float* __restrict__ x,          // [NROWS][DDIM]
        const float* __restrict__ weight,     // [E][D]
        const float* __restrict__ sigma_w,    // [E][D]
        const float* __restrict__ bias,       // [E]
        const float* __restrict__ sigma_b,    // [E]
        const float* __restrict__ eps_in,     // [D]
        const float* __restrict__ eps_out,    // [E]
        float* __restrict__ out_router,       // [NROWS][E]
        float* __restrict__ out_idx,          // [NROWS][2] stored as float
        float* __restrict__ zpart) {          // [ZN]
    __shared__ float4 wlds[2][NEXP * 64];   // 2 x 16 KiB chunks, [16][64] float4

    const int tid  = threadIdx.x;
    const int wv   = tid >> 6;              // 0..3
    const int lane = tid & 63;

    const int rowBase = blockIdx.x * 16 + wv * 4;
    const float4* xr0 = (const float4*)(x + (size_t)(rowBase + 0) * DDIM);
    const float4* xr1 = (const float4*)(x + (size_t)(rowBase + 1) * DDIM);
    const float4* xr2 = (const float4*)(x + (size_t)(rowBase + 2) * DDIM);
    const float4* xr3 = (const float4*)(x + (size_t)(rowBase + 3) * DDIM);
    const float4* wsrc = (const float4*)weight;    // [16][512] float4
    const float4* ssrc = (const float4*)sigma_w;   // [16][512] float4
    const float4* eisrc = (const float4*)eps_in;   // [512] float4

    // This thread stages float4-column (lane) of experts e_j = j*4 + wv
    // (wave-uniform), j = 0..3.  fo_j = fnoise(eps_out[e_j]) loaded once.
    float fo0 = fnoise(eps_out[0 * 4 + wv]);
    float fo1 = fnoise(eps_out[1 * 4 + wv]);
    float fo2 = fnoise(eps_out[2 * 4 + wv]);
    float fo3 = fnoise(eps_out[3 * 4 + wv]);

    float acc[64];
    #pragma unroll
    for (int i = 0; i < 64; ++i) acc[i] = 0.0f;

    float4 xbuf[2][4];

    // ---- prologue: stage chunk 0 (load -> compute w' -> ds_write), load x0
    {
        float4 ei = eisrc[lane];
        float fi_x = fnoise(ei.x), fi_y = fnoise(ei.y);
        float fi_z = fnoise(ei.z), fi_w = fnoise(ei.w);
        #pragma unroll
        for (int j = 0; j < 4; ++j) {
            const float foj = (j == 0) ? fo0 : (j == 1) ? fo1 : (j == 2) ? fo2 : fo3;
            size_t g = (size_t)(j * 4 + wv) * 512 + lane;
            float4 w4 = wsrc[g];
            float4 s4 = ssrc[g];
            float4 r;
            r.x = w4.x + s4.x * foj * fi_x;
            r.y = w4.y + s4.y * foj * fi_y;
            r.z = w4.z + s4.z * foj * fi_z;
            r.w = w4.w + s4.w * foj * fi_w;
            wlds[0][j * 256 + wv * 64 + lane] = r;
        }
    }
    xbuf[0][0] = xr0[lane];
    xbuf[0][1] = xr1[lane];
    xbuf[0][2] = xr2[lane];
    xbuf[0][3] = xr3[lane];
    __syncthreads();   // chunk 0 published, x0 landed

    #pragma unroll
    for (int c = 0; c < 8; ++c) {           // 8 chunks of 64 float4 cols
        const int cb = c & 1;
        const int nb = cb ^ 1;
        const int xc = c & 1;
        const int xn = xc ^ 1;
        // (1) issue staging loads for chunk c+1 early (latency hidden by FMA)
        float4 w40, w41, w42, w43, s40, s41, s42, s43, ei;
        if (c < 7) {
            size_t col = (size_t)(c + 1) * 64 + lane;
            ei  = eisrc[col];
            w40 = wsrc[(size_t)(0 * 4 + wv) * 512 + col];
            s40 = ssrc[(size_t)(0 * 4 + wv) * 512 + col];
            w41 = wsrc[(size_t)(1 * 4 + wv) * 512 + col];
            s41 = ssrc[(size_t)(1 * 4 + wv) * 512 + col];
            w42 = wsrc[(size_t)(2 * 4 + wv) * 512 + col];
            s42 = ssrc[(size_t)(2 * 4 + wv) * 512 + col];
            w43 = wsrc[(size_t)(3 * 4 + wv) * 512 + col];
            s43 = ssrc[(size_t)(3 * 4 + wv) * 512 + col];
            // (2) x prefetch for chunk c+1 (consumed next chunk)
            int p = (c + 1) * 64 + lane;
            xbuf[xn][0] = xr0[p];
            xbuf[xn][1] = xr1[p];
            xbuf[xn][2] = xr2[p];
            xbuf[xn][3] = xr3[p];
        }
        // (3) FMA body for chunk c (reads wlds[cb])
        #pragma unroll
        for (int e = 0; e < 16; ++e) {
            float4 w = wlds[cb][e * 64 + lane];
            float s0 = acc[0 * 16 + e];
            float s1 = acc[1 * 16 + e];
            float s2 = acc[2 * 16 + e];
            float s3 = acc[3 * 16 + e];
            s0 = fmaf(xbuf[xc][0].x, w.x, s0); s0 = fmaf(xbuf[xc][0].y, w.y, s0);
            s0 = fmaf(xbuf[xc][0].z, w.z, s0); s0 = fmaf(xbuf[xc][0].w, w.w, s0);
            s1 = fmaf(xbuf[xc][1].x, w.x, s1); s1 = fmaf(xbuf[xc][1].y, w.y, s1);
            s1 = fmaf(xbuf[xc][1].z, w.z, s1); s1 = fmaf(xbuf[xc][1].w, w.w, s1);
            s2 = fmaf(xbuf[xc][2].x, w.x, s2); s2 = fmaf(xbuf[xc][2].y, w.y, s2);
            s2 = fmaf(xbuf[xc][2].z, w.z, s2); s2 = fmaf(xbuf[xc][2].w, w.w, s2);
            s3 = fmaf(xbuf[xc][3].x, w.x, s3); s3 = fmaf(xbuf[xc][3].y, w.y, s3);
            s3 = fmaf(xbuf[xc][3].z, w.z, s3); s3 = fmaf(xbuf[xc][3].w, w.w, s3);
            acc[0 * 16 + e] = s0;
            acc[1 * 16 + e] = s1;
            acc[2 * 16 + e] = s2;
            acc[3 * 16 + e] = s3;
        }
        // (4) compute w' for chunk c+1 and publish to the other buffer
        if (c < 7) {
            float fi_x = fnoise(ei.x), fi_y = fnoise(ei.y);
            float fi_z = fnoise(ei.z), fi_w = fnoise(ei.w);
            float4 r;
            r.x = w40.x + s40.x * fo0 * fi_x;  r.y = w40.y + s40.y * fo0 * fi_y;
            r.z = w40.z + s40.z * fo0 * fi_z;  r.w = w40.w + s40.w * fo0 * fi_w;
            wlds[nb][0 * 256 + wv * 64 + lane] = r;
            r.x = w41.x + s41.x * fo1 * fi_x;  r.y = w41.y + s41.y * fo1 * fi_y;
            r.z = w41.z + s41.z * fo1 * fi_z;  r.w = w41.w + s41.w * fo1 * fi_w;
            wlds[nb][1 * 256 + wv * 64 + lane] = r;
            r.x = w42.x + s42.x * fo2 * fi_x;  r.y = w42.y + s42.y * fo2 * fi_y;
            r.z = w42.z + s42.z * fo2 * fi_z;  r.w = w42.w + s42.w * fo2 * fi_w;
            wlds[nb][2 * 256 + wv * 64 + lane] = r;
            r.x = w43.x + s43.x * fo3 * fi_x;  r.y = w43.y + s43.y * fo3 * fi_y;
            r.z = w43.z + s43.z * fo3 * fi_z;  r.w = w43.w + s43.w * fo3 * fi_w;
            wlds[nb][3 * 256 + wv * 64 + lane] = r;
            __syncthreads();   // chunk c+1 published; all waves done reading cb
        }
    }

    // Butterfly transpose-reduce: lane l ends with full sum of index l
    // (l = r*16 + e over this wave's 4 rows x 16 experts).
    #pragma unroll
    for (int half = 32; half >= 1; half >>= 1) {
        #pragma unroll
        for (int i = 0; i < half; ++i) {
            bool hi = (lane & half) != 0;
            float keep = hi ? acc[i + half] : acc[i];
            float send = hi ? acc[i] : acc[i + half];
            float recv = __shfl_xor(send, half, 64);
            acc[i] = keep + recv;
        }
    }

    const int e = lane & 15;           // expert owned by this lane
    const int r = lane >> 4;           // local row 0..3
    const int row = rowBase + r;
    // b_noisy computed inline (exact prep expression tree)
    float logit = acc[0] + (bias[e] + sigma_b[e] * fnoise(eps_out[e]));

    // top-1 with lower-index tie-break within the 16-lane group
    float m1 = logit; int i1 = e;
    #pragma unroll
    for (int off = 8; off >= 1; off >>= 1) {
        float om = __shfl_xor(m1, off, 64);
        int   oi = __shfl_xor(i1, off, 64);
        if (om > m1 || (om == m1 && oi < i1)) { m1 = om; i1 = oi; }
    }
    // top-2: mask out i1
    float v2 = (e == i1) ? -3.4e38f : logit;
    float m2 = v2; int i2 = e;
    #pragma unroll
    for (int off = 8; off >= 1; off >>= 1) {
        float om = __shfl_xor(m2, off, 64);
        int   oi = __shfl_xor(i2, off, 64);
        if (om > m2 || (om == m2 && oi < i2)) { m2 = om; i2 = oi; }
    }

    // softmax over sparse logits: exp(-1e30 - m1) == 0 exactly, so only
    // positions i1, i2 are nonzero.
    float t = expf(m2 - m1);
    float p1 = 1.0f / (1.0f + t);
    float val = (e == i1) ? p1 : ((e == i2) ? t * p1 : 0.0f);
    out_router[(size_t)rowBase * NEXP + lane] = val;   // fully coalesced

    if (e < 2) {
        out_idx[(size_t)row * 2 + e] = (float)((e == 0) ? i1 : i2);
    }

    // z-loss partial: sum lse^2 over this wave's 4 rows, no atomics.
    float zv = 0.0f;
    if (e == 0) {
        float lse = m1 + log1pf(t);
        zv = lse * lse;
    }
    zv += __shfl_xor(zv, 16, 64);
    zv += __shfl_xor(zv, 32, 64);
    if (lane == 0) {
        zpart[blockIdx.x * WPB + wv] = zv;
    }
}

__global__ void finalize_kernel(const float* __restrict__ zpart,
                                float* __restrict__ out) {
    __shared__ float ws4[4];
    int tid = threadIdx.x;   // 256 threads
    float s = 0.0f;
    for (int i = tid; i < ZN; i += 256) s += zpart[i];
    #pragma unroll
    for (int off = 32; off >= 1; off >>= 1) s += __shfl_xor(s, off, 64);
    if ((tid & 63) == 0) ws4[tid >> 6] = s;
    __syncthreads();
    if (tid == 0) {
        float total = ws4[0] + ws4[1] + ws4[2] + ws4[3];
        out[NROWS * NEXP + NROWS * 2] = total * (1.0f / (float)NROWS);
    }
}

extern "C" void kernel_launch(void* const* d_in, const int* in_sizes, int n_in,
                              void* d_out, int out_size, void* d_ws, size_t ws_size,
                              hipStream_t stream) {
    const float* mh      = (const float*)d_in[0];
    const float* weight  = (const float*)d_in[1];
    const float* sigw    = (const float*)d_in[2];
    const float* bias    = (const float*)d_in[3];
    const float* sigb    = (const float*)d_in[4];
    const float* eps_in  = (const float*)d_in[5];
    const float* eps_out = (const float*)d_in[6];

    float* out   = (float*)d_out;
    float* zpart = (float*)d_ws + 32800;   // 128B-aligned, matches prior layout

    router_kernel<<<RBLOCKS, 256, 0, stream>>>(
        mh, weight, sigw, bias, sigb, eps_in, eps_out,
        out, out + NROWS * NEXP, zpart);

    finalize_kernel<<<1, 256, 0, stream>>>(zpart, out);
}

// Round 9
// 218.367 us; speedup vs baseline: 1.0024x; 1.0024x over previous
//
#include <hip/hip_runtime.h>
#include <math.h>

#define NROWS 16384   // B*T
#define DDIM  2048
#define NEXP  16
#define RBLOCKS 1024  // router grid: 16 rows/block (8 waves x 2 rows)
#define WPB 8         // waves per 512-thread block
#define ZN (RBLOCKS * WPB)

__device__ __forceinline__ float fnoise(float x) {
    return copysignf(sqrtf(fabsf(x)), x);
}

// async 16B global -> LDS (no VGPR round-trip). Pass the wave-uniform LDS
// base; HW adds lane*16. Source pointer includes +lane.
__device__ __forceinline__ void async_copy16(const float4* g, float4* l) {
    __builtin_amdgcn_global_load_lds(
        (const __attribute__((address_space(1))) void*)g,
        (__attribute__((address_space(3))) void*)l, 16, 0, 0);
}

// ws layout (float idx):
//   [0, 32768)       w_noisy [E][D]
//   [32768, 32784)   b_noisy [E]
//   [32800, 41000)   zpartial [ZN] (one float per wave)

// Vectorized prep (verified): 8192 threads x float4.
__global__ void prep_kernel(const float* __restrict__ weight,
                            const float* __restrict__ sigma_weight,
                            const float* __restrict__ bias,
                            const float* __restrict__ sigma_bias,
                            const float* __restrict__ eps_in,
                            const float* __restrict__ eps_out,
                            float* __restrict__ w_noisy,
                            float* __restrict__ b_noisy) {
    int gid = blockIdx.x * blockDim.x + threadIdx.x;   // 0 .. 8191 (float4 idx)
    int e  = gid >> 9;          // 512 float4 per expert row
    int c4 = gid & 511;         // float4 column
    float4 w  = ((const float4*)weight)[gid];
    float4 sw = ((const float4*)sigma_weight)[gid];
    float4 ei = ((const float4*)eps_in)[c4];
    float fo = fnoise(eps_out[e]);
    float4 r;
    r.x = w.x + sw.x * fo * fnoise(ei.x);
    r.y = w.y + sw.y * fo * fnoise(ei.y);
    r.z = w.z + sw.z * fo * fnoise(ei.z);
    r.w = w.w + sw.w * fo * fnoise(ei.w);
    ((float4*)w_noisy)[gid] = r;
    if (gid < 4) {   // experts 4*gid .. 4*gid+3
        float4 b  = ((const float4*)bias)[gid];
        float4 sb = ((const float4*)sigma_bias)[gid];
        float4 eo = ((const float4*)eps_out)[gid];
        float4 rb;
        rb.x = b.x + sb.x * fnoise(eo.x);
        rb.y = b.y + sb.y * fnoise(eo.y);
        rb.z = b.z + sb.z * fnoise(eo.z);
        rb.w = b.w + sb.w * fnoise(eo.w);
        ((float4*)b_noisy)[gid] = rb;
    }
}

// Wave-rich router. Evidence R0-R8: all 16-wave/CU schedules plateau at
// router ~70 us with no pipe >25% busy -> latency starvation at 4 waves/SIMD.
// This version halves per-wave state (2 rows/wave, acc[32]) so the register
// cap drops to ~85 (__launch_bounds__(512,6)) -> 3 blocks/CU x 8 waves =
// 24 waves/CU (6/SIMD, 1.5x). Same total FMA/LDS/HBM work; LDS read traffic
// doubles (per-read reuse halves) - LDS pipe has the headroom. Staging,
// FMA expression tree, top-k, and z-loss are the verified R6 code restricted
// to 2 rows; butterfly = fold(lane^32) + 5-stage, lanes 32-63 are exact
// duplicates, writes gated to lane<32.
__global__ __launch_bounds__(512, 6) void router_kernel(
        const float* __restrict__ x,        // [NROWS][DDIM]
        const float* __restrict__ w_noisy,  // [E][D]
        const float* __restrict__ b_noisy,  // [E]
        float* __restrict__ out_router,     // [NROWS][E]
        float* __restrict__ out_idx,        // [NROWS][2] stored as float
        float* __restrict__ zpart) {        // [ZN]
    __shared__ float4 wlds[2][NEXP * 64];   // 2 x 16 KiB chunks, [16][64] float4

    const int tid  = threadIdx.x;
    const int wv   = tid >> 6;              // 0..7
    const int lane = tid & 63;

    const int rowBase = blockIdx.x * 16 + wv * 2;
    const float4* xr0 = (const float4*)(x + (size_t)(rowBase + 0) * DDIM);
    const float4* xr1 = (const float4*)(x + (size_t)(rowBase + 1) * DDIM);
    const float4* wsrc = (const float4*)w_noisy;  // [16][512] float4

    float acc[32];
    #pragma unroll
    for (int i = 0; i < 32; ++i) acc[i] = 0.0f;

    float4 xbuf[2][2];

    // ---- prologue: stage chunk 0 -> wlds[0] (16x64 float4, 2/thread);
    // flat float4 idx fb = j*512 + wv*64 (wave-uniform, 64-aligned), expert
    // e = fb>>6 = j*8+wv; src = wsrc[e*512 + c*64 + lane].
    #pragma unroll
    for (int j = 0; j < 2; ++j) {
        int fb = j * 512 + wv * 64;
        async_copy16(wsrc + (size_t)(fb >> 6) * 512 + lane, &wlds[0][fb]);
    }
    xbuf[0][0] = xr0[lane];
    xbuf[0][1] = xr1[lane];
    __syncthreads();   // chunk 0 in LDS (vmcnt(0) drain), x0 landed

    #pragma unroll
    for (int c = 0; c < 8; ++c) {           // 8 chunks of 64 float4 cols
        const int cb = c & 1;
        const int nb = cb ^ 1;
        const int xc = c & 1;
        const int xn = xc ^ 1;
        if (c < 7) {
            // stage chunk c+1 into the other buffer; drained by the
            // end-of-chunk __syncthreads
            #pragma unroll
            for (int j = 0; j < 2; ++j) {
                int fb = j * 512 + wv * 64;
                async_copy16(wsrc + (size_t)(fb >> 6) * 512 + (c + 1) * 64 + lane,
                             &wlds[nb][fb]);
            }
            // x prefetch for chunk c+1 (consumed next chunk)
            int p = (c + 1) * 64 + lane;
            xbuf[xn][0] = xr0[p];
            xbuf[xn][1] = xr1[p];
        }
        #pragma unroll
        for (int e = 0; e < 16; ++e) {
            float4 w = wlds[cb][e * 64 + lane];
            float s0 = acc[e];
            float s1 = acc[16 + e];
            s0 = fmaf(xbuf[xc][0].x, w.x, s0); s0 = fmaf(xbuf[xc][0].y, w.y, s0);
            s0 = fmaf(xbuf[xc][0].z, w.z, s0); s0 = fmaf(xbuf[xc][0].w, w.w, s0);
            s1 = fmaf(xbuf[xc][1].x, w.x, s1); s1 = fmaf(xbuf[xc][1].y, w.y, s1);
            s1 = fmaf(xbuf[xc][1].z, w.z, s1); s1 = fmaf(xbuf[xc][1].w, w.w, s1);
            acc[e]      = s0;
            acc[16 + e] = s1;
        }
        if (c < 7) __syncthreads();   // chunk c+1 landed; all waves done with c
    }

    // Fold lanes l and l+32 (same 32 (r,e) indices, disjoint columns):
    // afterwards lanes 32-63 hold values identical to lanes 0-31.
    #pragma unroll
    for (int i = 0; i < 32; ++i) acc[i] += __shfl_xor(acc[i], 32, 64);
    // 5-stage butterfly transpose-reduce within each 32-lane half: lane l
    // ends with the full sum of index (l&31) = r*16+e in acc[0].
    #pragma unroll
    for (int half = 16; half >= 1; half >>= 1) {
        #pragma unroll
        for (int i = 0; i < half; ++i) {
            bool hi = (lane & half) != 0;
            float keep = hi ? acc[i + half] : acc[i];
            float send = hi ? acc[i] : acc[i + half];
            float recv = __shfl_xor(send, half, 64);
            acc[i] = keep + recv;
        }
    }

    const int e = lane & 15;           // expert owned by this lane
    const int r = (lane >> 4) & 1;     // local row 0..1
    const int row = rowBase + r;
    float logit = acc[0] + b_noisy[e];

    // top-1 with lower-index tie-break within the 16-lane group
    float m1 = logit; int i1 = e;
    #pragma unroll
    for (int off = 8; off >= 1; off >>= 1) {
        float om = __shfl_xor(m1, off, 64);
        int   oi = __shfl_xor(i1, off, 64);
        if (om > m1 || (om == m1 && oi < i1)) { m1 = om; i1 = oi; }
    }
    // top-2: mask out i1
    float v2 = (e == i1) ? -3.4e38f : logit;
    float m2 = v2; int i2 = e;
    #pragma unroll
    for (int off = 8; off >= 1; off >>= 1) {
        float om = __shfl_xor(m2, off, 64);
        int   oi = __shfl_xor(i2, off, 64);
        if (om > m2 || (om == m2 && oi < i2)) { m2 = om; i2 = oi; }
    }

    // softmax over sparse logits: exp(-1e30 - m1) == 0 exactly, so only
    // positions i1, i2 are nonzero.
    float t = expf(m2 - m1);
    float p1 = 1.0f / (1.0f + t);
    float val = (e == i1) ? p1 : ((e == i2) ? t * p1 : 0.0f);
    if (lane < 32) {                       // lanes 32-63 are duplicates
        out_router[(size_t)rowBase * NEXP + lane] = val;   // 2 rows, coalesced
        if (e < 2) {
            out_idx[(size_t)row * 2 + e] = (float)((e == 0) ? i1 : i2);
        }
    }

    // z-loss partial: sum lse^2 over this wave's 2 rows, no atomics.
    float zv = 0.0f;
    if (e == 0 && lane < 32) {             // lanes 0 and 16 (rows 0,1)
        float lse = m1 + log1pf(t);
        zv = lse * lse;
    }
    zv += __shfl_xor(zv, 16, 64);
    zv += __shfl_xor(zv, 32, 64);          // partners are zero
    if (lane == 0) {
        zpart[blockIdx.x * WPB + wv] = zv;
    }
}

__global__ void finalize_kernel(const float* __restrict__ zpart,
                                float* __restrict__ out) {
    __shared__ float ws4[4];
    int tid = threadIdx.x;   // 256 threads
    float s = 0.0f;
    for (int i = tid; i < ZN; i += 256) s += zpart[i];
    #pragma unroll
    for (int off = 32; off >= 1; off >>= 1) s += __shfl_xor(s, off, 64);
    if ((tid & 63) == 0) ws4[tid >> 6] = s;
    __syncthreads();
    if (tid == 0) {
        float total = ws4[0] + ws4[1] + ws4[2] + ws4[3];
        out[NROWS * NEXP + NROWS * 2] = total * (1.0f / (float)NROWS);
    }
}

extern "C" void kernel_launch(void* const* d_in, const int* in_sizes, int n_in,
                              void* d_out, int out_size, void* d_ws, size_t ws_size,
                              hipStream_t stream) {
    const float* mh      = (const float*)d_in[0];
    const float* weight  = (const float*)d_in[1];
    const float* sigw    = (const float*)d_in[2];
    const float* bias    = (const float*)d_in[3];
    const float* sigb    = (const float*)d_in[4];
    const float* eps_in  = (const float*)d_in[5];
    const float* eps_out = (const float*)d_in[6];

    float* out      = (float*)d_out;
    float* w_noisy  = (float*)d_ws;
    float* b_noisy  = w_noisy + NEXP * DDIM;     // float idx 32768
    float* zpart    = w_noisy + 32800;           // float idx 32800, 128B-aligned

    prep_kernel<<<32, 256, 0, stream>>>(
        weight, sigw, bias, sigb, eps_in, eps_out, w_noisy, b_noisy);

    router_kernel<<<RBLOCKS, 512, 0, stream>>>(
        mh, w_noisy, b_noisy, out, out + NROWS * NEXP, zpart);

    finalize_kernel<<<1, 256, 0, stream>>>(zpart, out);
}